// Round 9
// baseline (220.647 us; speedup 1.0000x reference)
//
#include <hip/hip_runtime.h>

#define HW 1659      // 21*79
#define PADID 4096
#define EMB 20
#define HID 32
#define MAXLEN 64

// ---------------- Kernel 0: proj[g][j] = emb_table[g] . W_ih[j]  ---------------
__global__ __launch_bounds__(128) void proj_kernel(
    const float* __restrict__ emb_table, const float* __restrict__ W_ih,
    float* __restrict__ proj)
{
    const int tid = threadIdx.x;
    const int g = blockIdx.x * 4 + (tid >> 5);
    const int j = tid & 31;
    if (g > PADID) return;               // 4097 rows (row 4096 = zeros)
    const float* er = emb_table + (size_t)g * EMB;
    const float* wr = W_ih + j * EMB;
    float s = 0.f;
#pragma unroll
    for (int k = 0; k < EMB; k++) s += wr[k] * er[k];
    proj[(size_t)g * HID + j] = s;
}

// ---------------- Kernel 1: presence bytes -> scan -> bag -> emb gather --------
// R4 structure + presence loads hoisted into registers (4 loads in flight)
__global__ __launch_bounds__(256) void bag_emb_kernel(
    const int* __restrict__ chars, const int* __restrict__ colors,
    const float* __restrict__ emb_table,
    float* __restrict__ out_emb, float* __restrict__ out_bag)
{
    __shared__ unsigned char pres[4096];
    __shared__ int bagl[64];
    __shared__ int wsum[4];

    const int b   = blockIdx.x;
    const int tid = threadIdx.x;
    const int lane = tid & 63;
    const int wv   = tid >> 6;

    // ---- hoisted global loads (issue before LDS init/barrier) ----
    const int base = b * HW;
    const int pe = (4 - (base & 3)) & 3;          // peel to 16B alignment
    const int nv = (HW - pe) >> 2;                // 413/414 int4 groups
    const int nt = HW - pe - (nv << 2);           // tail 0..3
    const int4* c4 = (const int4*)(chars + base + pe);
    const int4* k4 = (const int4*)(colors + base + pe);

    int4 ca = c4[tid], ka = k4[tid];              // tid < nv always (nv>=413)
    const bool has2 = (tid + 256) < nv;
    const int i2 = has2 ? tid + 256 : tid;
    int4 cb = c4[i2], kb = k4[i2];
    int gp = -1, gt = -1;
    if (tid < pe) gp = (chars[base + tid] << 4) + colors[base + tid];
    if (tid < nt) {
        int i = base + pe + (nv << 2) + tid;
        gt = (chars[i] << 4) + colors[i];
    }

    ((uint4*)pres)[tid] = make_uint4(0u, 0u, 0u, 0u);
    if (tid < 64) bagl[tid] = PADID;
    __syncthreads();

    // ---- scatter presence bytes (idempotent, no atomics) ----
    pres[(ca.x << 4) + ka.x] = 1;
    pres[(ca.y << 4) + ka.y] = 1;
    pres[(ca.z << 4) + ka.z] = 1;
    pres[(ca.w << 4) + ka.w] = 1;
    if (has2) {
        pres[(cb.x << 4) + kb.x] = 1;
        pres[(cb.y << 4) + kb.y] = 1;
        pres[(cb.z << 4) + kb.z] = 1;
        pres[(cb.w << 4) + kb.w] = 1;
    }
    if (gp >= 0) pres[gp] = 1;
    if (gt >= 0) pres[gt] = 1;
    __syncthreads();

    // ---- each thread owns 16 ids; count + block exclusive scan ----
    uint4 w4 = ((const uint4*)pres)[tid];
    const unsigned M = 0x01010101u;
    int cnt = __popc(w4.x & M) + __popc(w4.y & M)
            + __popc(w4.z & M) + __popc(w4.w & M);

    int pre = cnt;
#pragma unroll
    for (int d = 1; d < 64; d <<= 1) {
        int v = __shfl_up(pre, d, 64);
        if (lane >= d) pre += v;
    }
    if (lane == 63) wsum[wv] = pre;
    __syncthreads();
    int wbase = 0;
#pragma unroll
    for (int w2 = 0; w2 < 4; w2++) wbase += (w2 < wv) ? wsum[w2] : 0;
    int p = wbase + pre - cnt;

    unsigned wrd[4] = {w4.x, w4.y, w4.z, w4.w};
#pragma unroll
    for (int c = 0; c < 4; c++) {
#pragma unroll
        for (int k = 0; k < 4; k++) {
            if ((wrd[c] >> (8 * k)) & 1) {
                if (p < 64) bagl[p] = 16 * tid + 4 * c + k;
                p++;
            }
        }
    }
    __syncthreads();

    if (tid < 64) out_bag[(size_t)b * 64 + tid] = (float)bagl[tid];

    const float4* tab4 = (const float4*)emb_table;
    float4* dst4 = (float4*)(out_emb + (size_t)b * (MAXLEN * EMB));
    for (int q = tid; q < MAXLEN * 5; q += 256) {
        int t = q / 5;
        int m = q - t * 5;
        int row = bagl[t];
        dst4[q] = tab4[row * 5 + m];
    }
}

// ---------------- Kernel 2: packed RNN, fence-free LDS exchange ----------------
// The h-row reads go through an opaque pointer (asm "+v" null op): the compiler
// can't CSE them across steps and can't reorder them past the may-aliasing h
// store, but GLOBAL loads (proj/bag) move freely -> prefetch pipelines across
// steps. HW: same-wave LDS ops execute in order; compiler inserts lgkmcnt
// before data use. No s_barrier, no memory-clobber fence.
__global__ __launch_bounds__(128, 4) void rnn_kernel(
    const float* __restrict__ proj, const float* __restrict__ bagf,
    const float* __restrict__ W_hh,
    const float* __restrict__ b_ih, const float* __restrict__ b_hh,
    float* __restrict__ out_h)
{
    __shared__ float hbuf[4][32];   // row per sample; rows 2w,2w+1 owned by wave w

    const int tid = threadIdx.x;
    const int ib  = tid >> 5;          // sample slot 0..3
    const int j   = tid & 31;          // hidden unit
    const int b   = blockIdx.x * 4 + ib;

    float whh[HID];
#pragma unroll
    for (int k = 0; k < HID; k++) whh[k] = W_hh[j * HID + k];
    const float sbias = b_ih[j] + b_hh[j];

    // sequence length from sorted bag via one ballot (padding id == 4096)
    const float* bp = bagf + (size_t)b * 64;
    unsigned long long m0 = __ballot(bp[j]      < 4095.5f);
    unsigned long long m1 = __ballot(bp[32 + j] < 4095.5f);
    const int half = ib & 1;
    const int len = __popc((unsigned)(m0 >> (half * 32)))
                  + __popc((unsigned)(m1 >> (half * 32)));

    hbuf[ib][j] = 0.f;                 // same wave later reads it: in-order pipe

    const float* hbp = &hbuf[ib][0];
    float h = 0.f;
    float pv_next = proj[(int)bp[0] * HID + j];   // prefetch depth 1

    for (int t = 0; t < MAXLEN; t++) {
        const float pv = pv_next;
        const int tn = (t + 1 < MAXLEN) ? (t + 1) : t;
        pv_next = proj[(int)bp[tn] * HID + j];    // free to stay in flight

        const float* p = hbp;
        asm("" : "+v"(p));             // opaque: defeat CSE, no memory clobber
        const float4* hb4 = (const float4*)p;
        float4 hv0 = hb4[0], hv1 = hb4[1], hv2 = hb4[2], hv3 = hb4[3];
        float4 hv4 = hb4[4], hv5 = hb4[5], hv6 = hb4[6], hv7 = hb4[7];

        float s0 = sbias + pv, s1 = 0.f, s2 = 0.f, s3 = 0.f;
        s0 += whh[0]*hv0.x + whh[1]*hv0.y + whh[2]*hv0.z + whh[3]*hv0.w;
        s1 += whh[4]*hv1.x + whh[5]*hv1.y + whh[6]*hv1.z + whh[7]*hv1.w;
        s2 += whh[8]*hv2.x + whh[9]*hv2.y + whh[10]*hv2.z + whh[11]*hv2.w;
        s3 += whh[12]*hv3.x + whh[13]*hv3.y + whh[14]*hv3.z + whh[15]*hv3.w;
        s0 += whh[16]*hv4.x + whh[17]*hv4.y + whh[18]*hv4.z + whh[19]*hv4.w;
        s1 += whh[20]*hv5.x + whh[21]*hv5.y + whh[22]*hv5.z + whh[23]*hv5.w;
        s2 += whh[24]*hv6.x + whh[25]*hv6.y + whh[26]*hv6.z + whh[27]*hv6.w;
        s3 += whh[28]*hv7.x + whh[29]*hv7.y + whh[30]*hv7.z + whh[31]*hv7.w;
        float s = (s0 + s1) + (s2 + s3);

        // fast tanh: (e^{2s}-1)/(e^{2s}+1), clamped so exp never overflows
        s = fminf(fmaxf(s, -9.f), 9.f);
        float e = __expf(2.f * s);
        float th = (e - 1.f) * __builtin_amdgcn_rcpf(e + 1.f);

        h = (t < len) ? th : h;        // freeze past sequence length

        hbuf[ib][j] = h;               // may-alias the opaque reads -> ordered
    }

    out_h[(size_t)b * HID + j] = h;
}

// ---------------- Fallback RNN (R4 exact) if ws can't hold proj ----------------
__global__ __launch_bounds__(128, 4) void rnn_kernel_noproj(
    const float* __restrict__ emb, const float* __restrict__ bagf,
    const float* __restrict__ W_ih, const float* __restrict__ W_hh,
    const float* __restrict__ b_ih, const float* __restrict__ b_hh,
    float* __restrict__ out_h)
{
    __shared__ float hbuf[4][32];
    const int tid = threadIdx.x;
    const int ib  = tid >> 5;
    const int j   = tid & 31;
    const int b   = blockIdx.x * 4 + ib;

    float wih[EMB];
#pragma unroll
    for (int k = 0; k < EMB; k++) wih[k] = W_ih[j * EMB + k];
    float whh[HID];
#pragma unroll
    for (int k = 0; k < HID; k++) whh[k] = W_hh[j * HID + k];
    const float sbias = b_ih[j] + b_hh[j];

    const float* bp = bagf + (size_t)b * 64;
    unsigned long long m0 = __ballot(bp[j]      < 4095.5f);
    unsigned long long m1 = __ballot(bp[32 + j] < 4095.5f);
    const int half = ib & 1;
    const int len = __popc((unsigned)(m0 >> (half * 32)))
                  + __popc((unsigned)(m1 >> (half * 32)));

    hbuf[ib][j] = 0.f;
    asm volatile("s_waitcnt lgkmcnt(0)" ::: "memory");

    float h = 0.f;
    const float* xb = emb + (size_t)b * (MAXLEN * EMB);
    for (int t = 0; t < MAXLEN; t++) {
        const float4* xp = (const float4*)(xb + t * EMB);
        float4 x0 = xp[0], x1 = xp[1], x2 = xp[2], x3 = xp[3], x4 = xp[4];
        float s = sbias;
        const float4* hb4 = (const float4*)hbuf[ib];
#pragma unroll
        for (int m = 0; m < 8; m++) {
            float4 hv = hb4[m];
            s += whh[4*m+0]*hv.x + whh[4*m+1]*hv.y
               + whh[4*m+2]*hv.z + whh[4*m+3]*hv.w;
        }
        s += wih[0]*x0.x + wih[1]*x0.y + wih[2]*x0.z + wih[3]*x0.w;
        s += wih[4]*x1.x + wih[5]*x1.y + wih[6]*x1.z + wih[7]*x1.w;
        s += wih[8]*x2.x + wih[9]*x2.y + wih[10]*x2.z + wih[11]*x2.w;
        s += wih[12]*x3.x + wih[13]*x3.y + wih[14]*x3.z + wih[15]*x3.w;
        s += wih[16]*x4.x + wih[17]*x4.y + wih[18]*x4.z + wih[19]*x4.w;
        s = fminf(fmaxf(s, -9.f), 9.f);
        float e = __expf(2.f * s);
        float th = (e - 1.f) * __builtin_amdgcn_rcpf(e + 1.f);
        h = (t < len) ? th : h;
        hbuf[ib][j] = h;
        asm volatile("s_waitcnt lgkmcnt(0)" ::: "memory");
    }
    out_h[(size_t)b * HID + j] = h;
}

extern "C" void kernel_launch(void* const* d_in, const int* in_sizes, int n_in,
                              void* d_out, int out_size, void* d_ws, size_t ws_size,
                              hipStream_t stream) {
    const int*   chars     = (const int*)d_in[0];
    const int*   colors    = (const int*)d_in[1];
    const float* emb_table = (const float*)d_in[2];
    const float* W_ih      = (const float*)d_in[3];
    const float* W_hh      = (const float*)d_in[4];
    const float* b_ih      = (const float*)d_in[5];
    const float* b_hh      = (const float*)d_in[6];

    const int B = in_sizes[0] / HW;      // 8192

    float* out     = (float*)d_out;
    float* out_h   = out;                                    // [B, 32]
    float* out_emb = out + (size_t)B * HID;                  // [B, 64, 20]
    float* out_bag = out_emb + (size_t)B * MAXLEN * EMB;     // [B, 64]

    const size_t proj_bytes = (size_t)(PADID + 1) * HID * sizeof(float);

    bag_emb_kernel<<<B, 256, 0, stream>>>(chars, colors, emb_table, out_emb, out_bag);

    if (ws_size >= proj_bytes) {         // ws_size is fixed -> same path every call
        float* proj = (float*)d_ws;
        proj_kernel<<<(PADID + 1 + 3) / 4, 128, 0, stream>>>(emb_table, W_ih, proj);
        rnn_kernel<<<B / 4, 128, 0, stream>>>(proj, out_bag, W_hh, b_ih, b_hh, out_h);
    } else {
        rnn_kernel_noproj<<<B / 4, 128, 0, stream>>>(out_emb, out_bag, W_ih, W_hh,
                                                     b_ih, b_hh, out_h);
    }
}

// Round 10
// 194.497 us; speedup vs baseline: 1.1345x; 1.1345x over previous
//
#include <hip/hip_runtime.h>

#define HW 1659      // 21*79
#define PADID 4096
#define EMB 20
#define HID 32
#define MAXLEN 64

// ---------------- Kernel 0: proj[g][j] = emb_table[g] . W_ih[j]  ---------------
__global__ __launch_bounds__(128) void proj_kernel(
    const float* __restrict__ emb_table, const float* __restrict__ W_ih,
    float* __restrict__ proj)
{
    const int tid = threadIdx.x;
    const int g = blockIdx.x * 4 + (tid >> 5);
    const int j = tid & 31;
    if (g > PADID) return;               // 4097 rows (row 4096 = zeros)
    const float* er = emb_table + (size_t)g * EMB;
    const float* wr = W_ih + j * EMB;
    float s = 0.f;
#pragma unroll
    for (int k = 0; k < EMB; k++) s += wr[k] * er[k];
    proj[(size_t)g * HID + j] = s;
}

// ---------------- Kernel 1: presence bytes -> scan -> bag -> emb gather --------
// R7 exact (proven 45 us)
__global__ __launch_bounds__(256) void bag_emb_kernel(
    const int* __restrict__ chars, const int* __restrict__ colors,
    const float* __restrict__ emb_table,
    float* __restrict__ out_emb, float* __restrict__ out_bag)
{
    __shared__ unsigned char pres[4096];
    __shared__ int bagl[64];
    __shared__ int wsum[4];

    const int b   = blockIdx.x;
    const int tid = threadIdx.x;
    const int lane = tid & 63;
    const int wv   = tid >> 6;

    ((uint4*)pres)[tid] = make_uint4(0u, 0u, 0u, 0u);
    if (tid < 64) bagl[tid] = PADID;
    __syncthreads();

    const int base = b * HW;
    const int pe = (4 - (base & 3)) & 3;          // peel to 16B alignment
    if (tid < pe) {
        int g = (chars[base + tid] << 4) + colors[base + tid];
        pres[g] = 1;
    }
    const int nv = (HW - pe) >> 2;
    const int nt = HW - pe - (nv << 2);
    const int4* c4 = (const int4*)(chars + base + pe);
    const int4* k4 = (const int4*)(colors + base + pe);
    for (int v = tid; v < nv; v += 256) {
        int4 c = c4[v], k = k4[v];
        pres[(c.x << 4) + k.x] = 1;
        pres[(c.y << 4) + k.y] = 1;
        pres[(c.z << 4) + k.z] = 1;
        pres[(c.w << 4) + k.w] = 1;
    }
    if (tid < nt) {
        int i = base + pe + (nv << 2) + tid;
        pres[(chars[i] << 4) + colors[i]] = 1;
    }
    __syncthreads();

    uint4 w4 = ((const uint4*)pres)[tid];
    const unsigned M = 0x01010101u;
    int cnt = __popc(w4.x & M) + __popc(w4.y & M)
            + __popc(w4.z & M) + __popc(w4.w & M);

    int pre = cnt;
#pragma unroll
    for (int d = 1; d < 64; d <<= 1) {
        int v = __shfl_up(pre, d, 64);
        if (lane >= d) pre += v;
    }
    if (lane == 63) wsum[wv] = pre;
    __syncthreads();
    int wbase = 0;
#pragma unroll
    for (int w2 = 0; w2 < 4; w2++) wbase += (w2 < wv) ? wsum[w2] : 0;
    int p = wbase + pre - cnt;

    unsigned wrd[4] = {w4.x, w4.y, w4.z, w4.w};
#pragma unroll
    for (int c = 0; c < 4; c++) {
#pragma unroll
        for (int k = 0; k < 4; k++) {
            if ((wrd[c] >> (8 * k)) & 1) {
                if (p < 64) bagl[p] = 16 * tid + 4 * c + k;
                p++;
            }
        }
    }
    __syncthreads();

    if (tid < 64) out_bag[(size_t)b * 64 + tid] = (float)bagl[tid];

    const float4* tab4 = (const float4*)emb_table;
    float4* dst4 = (float4*)(out_emb + (size_t)b * (MAXLEN * EMB));
    for (int q = tid; q < MAXLEN * 5; q += 256) {
        int t = q / 5;
        int m = q - t * 5;
        int row = bagl[t];
        dst4[q] = tab4[row * 5 + m];
    }
}

// ---------------- Kernel 2: packed RNN, 2 hidden units per lane ----------------
// 16 lanes/sample -> 4 samples/wave: a wave-step issues the SAME 9 LDS
// instructions (8 broadcast ds_read_b128 + 1 ds_write_b64) but serves 4
// samples (R7: 2) -> LDS-issue cost per sample halves. h stored interleaved:
// LDS slot 2m   = h_m, slot 2m+1 = h_{m+16}; W_hh columns permuted to match.
// h rows wave-private; R7's proven lgkmcnt fence, no block barrier.
__global__ __launch_bounds__(128, 4) void rnn_kernel(
    const float* __restrict__ proj, const float* __restrict__ bagf,
    const float* __restrict__ W_hh,
    const float* __restrict__ b_ih, const float* __restrict__ b_hh,
    float* __restrict__ out_h)
{
    __shared__ float hbuf[8][32];      // 8 samples/block; wave w owns rows 4w..4w+3

    const int tid  = threadIdx.x;
    const int wv   = tid >> 6;
    const int lane = tid & 63;
    const int sl   = lane >> 4;        // sample slot within wave 0..3
    const int ib   = wv * 4 + sl;      // sample slot within block 0..7
    const int jj   = lane & 15;        // handles hidden units jj and jj+16
    const int b    = blockIdx.x * 8 + ib;

    // W_hh rows jj and jj+16, columns permuted: slot k holds h_{(k&1)*16+(k>>1)}
    float w0[HID], w1[HID];
#pragma unroll
    for (int k = 0; k < HID; k++) {
        const int src = ((k & 1) << 4) + (k >> 1);
        w0[k] = W_hh[jj * HID + src];
        w1[k] = W_hh[(jj + 16) * HID + src];
    }
    const float sb0 = b_ih[jj] + b_hh[jj];
    const float sb1 = b_ih[jj + 16] + b_hh[jj + 16];

    const float* bps = bagf + (size_t)b * 64;

    // length: 4 strided reads + 4 ballots; 16-bit nibble per sample slot
    unsigned long long mm0 = __ballot(bps[jj]      < 4095.5f);
    unsigned long long mm1 = __ballot(bps[jj + 16] < 4095.5f);
    unsigned long long mm2 = __ballot(bps[jj + 32] < 4095.5f);
    unsigned long long mm3 = __ballot(bps[jj + 48] < 4095.5f);
    const int sh = sl * 16;
    const int len = __popc((unsigned)((mm0 >> sh) & 0xFFFFu))
                  + __popc((unsigned)((mm1 >> sh) & 0xFFFFu))
                  + __popc((unsigned)((mm2 >> sh) & 0xFFFFu))
                  + __popc((unsigned)((mm3 >> sh) & 0xFFFFu));

    ((float2*)hbuf[ib])[jj] = make_float2(0.f, 0.f);
    asm volatile("s_waitcnt lgkmcnt(0)" ::: "memory");   // wave-local fence

    float h0 = 0.f, h1 = 0.f;
    for (int t = 0; t < MAXLEN; t++) {
        const int idx = (int)bps[t];                      // broadcast per sample
        const float pv0 = proj[idx * HID + jj];
        const float pv1 = proj[idx * HID + jj + 16];

        const float4* hb4 = (const float4*)hbuf[ib];
        float a0 = sb0 + pv0, a1 = sb1 + pv1, c0 = 0.f, c1 = 0.f;
#pragma unroll
        for (int m = 0; m < 8; m += 2) {
            float4 u = hb4[m], v = hb4[m + 1];
            a0 += w0[4*m+0]*u.x + w0[4*m+1]*u.y + w0[4*m+2]*u.z + w0[4*m+3]*u.w;
            a1 += w1[4*m+0]*u.x + w1[4*m+1]*u.y + w1[4*m+2]*u.z + w1[4*m+3]*u.w;
            c0 += w0[4*m+4]*v.x + w0[4*m+5]*v.y + w0[4*m+6]*v.z + w0[4*m+7]*v.w;
            c1 += w1[4*m+4]*v.x + w1[4*m+5]*v.y + w1[4*m+6]*v.z + w1[4*m+7]*v.w;
        }
        float s0 = a0 + c0, s1 = a1 + c1;

        // fast tanh x2: (e^{2s}-1)/(e^{2s}+1), clamped
        s0 = fminf(fmaxf(s0, -9.f), 9.f);
        s1 = fminf(fmaxf(s1, -9.f), 9.f);
        float e0 = __expf(2.f * s0);
        float e1 = __expf(2.f * s1);
        float th0 = (e0 - 1.f) * __builtin_amdgcn_rcpf(e0 + 1.f);
        float th1 = (e1 - 1.f) * __builtin_amdgcn_rcpf(e1 + 1.f);

        h0 = (t < len) ? th0 : h0;
        h1 = (t < len) ? th1 : h1;

        ((float2*)hbuf[ib])[jj] = make_float2(h0, h1);   // one ds_write_b64
        asm volatile("s_waitcnt lgkmcnt(0)" ::: "memory");
    }

    out_h[(size_t)b * HID + jj]      = h0;
    out_h[(size_t)b * HID + jj + 16] = h1;
}

// ---------------- Fallback RNN (R4 exact) if ws can't hold proj ----------------
__global__ __launch_bounds__(128, 4) void rnn_kernel_noproj(
    const float* __restrict__ emb, const float* __restrict__ bagf,
    const float* __restrict__ W_ih, const float* __restrict__ W_hh,
    const float* __restrict__ b_ih, const float* __restrict__ b_hh,
    float* __restrict__ out_h)
{
    __shared__ float hbuf[4][32];
    const int tid = threadIdx.x;
    const int ib  = tid >> 5;
    const int j   = tid & 31;
    const int b   = blockIdx.x * 4 + ib;

    float wih[EMB];
#pragma unroll
    for (int k = 0; k < EMB; k++) wih[k] = W_ih[j * EMB + k];
    float whh[HID];
#pragma unroll
    for (int k = 0; k < HID; k++) whh[k] = W_hh[j * HID + k];
    const float sbias = b_ih[j] + b_hh[j];

    const float* bp = bagf + (size_t)b * 64;
    unsigned long long m0 = __ballot(bp[j]      < 4095.5f);
    unsigned long long m1 = __ballot(bp[32 + j] < 4095.5f);
    const int half = ib & 1;
    const int len = __popc((unsigned)(m0 >> (half * 32)))
                  + __popc((unsigned)(m1 >> (half * 32)));

    hbuf[ib][j] = 0.f;
    asm volatile("s_waitcnt lgkmcnt(0)" ::: "memory");

    float h = 0.f;
    const float* xb = emb + (size_t)b * (MAXLEN * EMB);
    for (int t = 0; t < MAXLEN; t++) {
        const float4* xp = (const float4*)(xb + t * EMB);
        float4 x0 = xp[0], x1 = xp[1], x2 = xp[2], x3 = xp[3], x4 = xp[4];
        float s = sbias;
        const float4* hb4 = (const float4*)hbuf[ib];
#pragma unroll
        for (int m = 0; m < 8; m++) {
            float4 hv = hb4[m];
            s += whh[4*m+0]*hv.x + whh[4*m+1]*hv.y
               + whh[4*m+2]*hv.z + whh[4*m+3]*hv.w;
        }
        s += wih[0]*x0.x + wih[1]*x0.y + wih[2]*x0.z + wih[3]*x0.w;
        s += wih[4]*x1.x + wih[5]*x1.y + wih[6]*x1.z + wih[7]*x1.w;
        s += wih[8]*x2.x + wih[9]*x2.y + wih[10]*x2.z + wih[11]*x2.w;
        s += wih[12]*x3.x + wih[13]*x3.y + wih[14]*x3.z + wih[15]*x3.w;
        s += wih[16]*x4.x + wih[17]*x4.y + wih[18]*x4.z + wih[19]*x4.w;
        s = fminf(fmaxf(s, -9.f), 9.f);
        float e = __expf(2.f * s);
        float th = (e - 1.f) * __builtin_amdgcn_rcpf(e + 1.f);
        h = (t < len) ? th : h;
        hbuf[ib][j] = h;
        asm volatile("s_waitcnt lgkmcnt(0)" ::: "memory");
    }
    out_h[(size_t)b * HID + j] = h;
}

extern "C" void kernel_launch(void* const* d_in, const int* in_sizes, int n_in,
                              void* d_out, int out_size, void* d_ws, size_t ws_size,
                              hipStream_t stream) {
    const int*   chars     = (const int*)d_in[0];
    const int*   colors    = (const int*)d_in[1];
    const float* emb_table = (const float*)d_in[2];
    const float* W_ih      = (const float*)d_in[3];
    const float* W_hh      = (const float*)d_in[4];
    const float* b_ih      = (const float*)d_in[5];
    const float* b_hh      = (const float*)d_in[6];

    const int B = in_sizes[0] / HW;      // 8192

    float* out     = (float*)d_out;
    float* out_h   = out;                                    // [B, 32]
    float* out_emb = out + (size_t)B * HID;                  // [B, 64, 20]
    float* out_bag = out_emb + (size_t)B * MAXLEN * EMB;     // [B, 64]

    const size_t proj_bytes = (size_t)(PADID + 1) * HID * sizeof(float);

    bag_emb_kernel<<<B, 256, 0, stream>>>(chars, colors, emb_table, out_emb, out_bag);

    if (ws_size >= proj_bytes) {         // ws_size is fixed -> same path every call
        float* proj = (float*)d_ws;
        proj_kernel<<<(PADID + 1 + 3) / 4, 128, 0, stream>>>(emb_table, W_ih, proj);
        rnn_kernel<<<B / 8, 128, 0, stream>>>(proj, out_bag, W_hh, b_ih, b_hh, out_h);
    } else {
        rnn_kernel_noproj<<<B / 4, 128, 0, stream>>>(out_emb, out_bag, W_ih, W_hh,
                                                     b_ih, b_hh, out_h);
    }
}

// Round 11
// 193.137 us; speedup vs baseline: 1.1424x; 1.0070x over previous
//
#include <hip/hip_runtime.h>

#define HW 1659      // 21*79
#define PADID 4096
#define EMB 20
#define HID 32
#define MAXLEN 64

typedef float v2f __attribute__((ext_vector_type(2)));

// ---------------- Kernel 0: proj[g][j] = emb_table[g] . W_ih[j]  ---------------
__global__ __launch_bounds__(128) void proj_kernel(
    const float* __restrict__ emb_table, const float* __restrict__ W_ih,
    float* __restrict__ proj)
{
    const int tid = threadIdx.x;
    const int g = blockIdx.x * 4 + (tid >> 5);
    const int j = tid & 31;
    if (g > PADID) return;               // 4097 rows (row 4096 = zeros)
    const float* er = emb_table + (size_t)g * EMB;
    const float* wr = W_ih + j * EMB;
    float s = 0.f;
#pragma unroll
    for (int k = 0; k < EMB; k++) s += wr[k] * er[k];
    proj[(size_t)g * HID + j] = s;
}

// ---------------- Kernel 1: one WAVE per sample, ZERO block barriers -----------
// 4 independent waves/block; wave-private presence bytes + lgkmcnt fences
// (proven in rnn since R4). Presence stored at SWIZZLED byte address
//   addr = g[5:4]<<10 | g[11:6]<<4 | g[3:0]
// so scan pass i reads uint4 index (i<<6)+lane = consecutive per lane
// (conflict-free) while lane ownership stays ids [64*lane, 64*lane+64).
__global__ __launch_bounds__(256) void bag_emb_kernel(
    const int* __restrict__ chars, const int* __restrict__ colors,
    const float* __restrict__ emb_table,
    float* __restrict__ out_emb, float* __restrict__ out_bag)
{
    __shared__ unsigned char pres[4][4096];
    __shared__ int bagl[4][64];

    const int tid  = threadIdx.x;
    const int wv   = tid >> 6;
    const int lane = tid & 63;
    const int b    = blockIdx.x * 4 + wv;

    unsigned char* pr = pres[wv];
    uint4* pz = (uint4*)pr;
#pragma unroll
    for (int i = 0; i < 4; i++) pz[lane + 64 * i] = make_uint4(0u, 0u, 0u, 0u);
    bagl[wv][lane] = PADID;
    asm volatile("s_waitcnt lgkmcnt(0)" ::: "memory");

    // ---- scatter presence (idempotent byte stores, swizzled addresses) ----
    const int base = b * HW;
    const int pe = (4 - (base & 3)) & 3;          // peel to 16B alignment
    if (lane < pe) {
        int g = (chars[base + lane] << 4) + colors[base + lane];
        pr[((g & 0x30) << 6) | ((g >> 6) << 4) | (g & 15)] = 1;
    }
    const int nv = (HW - pe) >> 2;
    const int nt = HW - pe - (nv << 2);
    const int4* c4 = (const int4*)(chars + base + pe);
    const int4* k4 = (const int4*)(colors + base + pe);
    for (int v = lane; v < nv; v += 64) {
        int4 c = c4[v], k = k4[v];
        int g0 = (c.x << 4) + k.x, g1 = (c.y << 4) + k.y;
        int g2 = (c.z << 4) + k.z, g3 = (c.w << 4) + k.w;
        pr[((g0 & 0x30) << 6) | ((g0 >> 6) << 4) | (g0 & 15)] = 1;
        pr[((g1 & 0x30) << 6) | ((g1 >> 6) << 4) | (g1 & 15)] = 1;
        pr[((g2 & 0x30) << 6) | ((g2 >> 6) << 4) | (g2 & 15)] = 1;
        pr[((g3 & 0x30) << 6) | ((g3 >> 6) << 4) | (g3 & 15)] = 1;
    }
    if (lane < nt) {
        int i = base + pe + (nv << 2) + lane;
        int g = (chars[i] << 4) + colors[i];
        pr[((g & 0x30) << 6) | ((g >> 6) << 4) | (g & 15)] = 1;
    }
    asm volatile("s_waitcnt lgkmcnt(0)" ::: "memory");

    // ---- count + wave scan; lane owns ids [64*lane, 64*lane+64) ----
    uint4 q0 = pz[lane], q1 = pz[lane + 64], q2 = pz[lane + 128], q3 = pz[lane + 192];
    const unsigned M = 0x01010101u;
    int cnt = __popc(q0.x & M) + __popc(q0.y & M) + __popc(q0.z & M) + __popc(q0.w & M)
            + __popc(q1.x & M) + __popc(q1.y & M) + __popc(q1.z & M) + __popc(q1.w & M)
            + __popc(q2.x & M) + __popc(q2.y & M) + __popc(q2.z & M) + __popc(q2.w & M)
            + __popc(q3.x & M) + __popc(q3.y & M) + __popc(q3.z & M) + __popc(q3.w & M);
    int pre = cnt;
#pragma unroll
    for (int d = 1; d < 64; d <<= 1) {
        int v = __shfl_up(pre, d, 64);
        if (lane >= d) pre += v;
    }
    int p = pre - cnt;                             // exclusive prefix

    // ---- extract (only the few lanes whose prefix < 64 do work) ----
    if (p < 64) {
        unsigned wrd[16] = {q0.x, q0.y, q0.z, q0.w, q1.x, q1.y, q1.z, q1.w,
                            q2.x, q2.y, q2.z, q2.w, q3.x, q3.y, q3.z, q3.w};
#pragma unroll
        for (int w = 0; w < 16; w++) {
            unsigned x = wrd[w];
#pragma unroll
            for (int k = 0; k < 4; k++) {
                if ((x >> (8 * k)) & 1) {
                    if (p < 64) bagl[wv][p] = 64 * lane + 4 * w + k;
                    p++;
                }
            }
        }
    }
    asm volatile("s_waitcnt lgkmcnt(0)" ::: "memory");

    // ---- bag write + gather (no barriers; loads pipeline freely) ----
    out_bag[(size_t)b * 64 + lane] = (float)bagl[wv][lane];

    const float4* tab4 = (const float4*)emb_table;
    float4* dst4 = (float4*)(out_emb + (size_t)b * (MAXLEN * EMB));
#pragma unroll
    for (int it = 0; it < 5; it++) {
        int q = lane + 64 * it;                    // 0..319
        int t = q / 5;
        int m = q - 5 * t;
        int row = bagl[wv][t];                     // row 4096 is the zero row
        dst4[q] = tab4[row * 5 + m];
    }
}

// ---------------- Kernel 2: packed RNN, 2 hidden units/lane, v_pk_fma ----------
// 16 lanes/sample, 4 samples/wave. Dot products packed over k-pairs
// (v_pk_fma_f32 via v2f fma): 32 packed FMA/lane-step instead of 64 scalar.
// proj loads prefetched depth-1 (idx depth-2) BEFORE the lgkmcnt fence:
// vmcnt stays in flight across it. tanh = 1 - 2/(e^{2s}+1): no clamp needed
// (e=inf -> 1, e=0 -> -1).
__global__ __launch_bounds__(128, 4) void rnn_kernel(
    const float* __restrict__ proj, const float* __restrict__ bagf,
    const float* __restrict__ W_hh,
    const float* __restrict__ b_ih, const float* __restrict__ b_hh,
    float* __restrict__ out_h)
{
    __shared__ float hbuf[8][32];      // 8 samples/block; wave w owns rows 4w..4w+3

    const int tid  = threadIdx.x;
    const int wv   = tid >> 6;
    const int lane = tid & 63;
    const int sl   = lane >> 4;        // sample slot within wave 0..3
    const int ib   = wv * 4 + sl;      // sample slot within block 0..7
    const int jj   = lane & 15;        // handles hidden units jj and jj+16
    const int b    = blockIdx.x * 8 + ib;

    // weights paired over k: w0p[m] = {W_hh[jj][2m], W_hh[jj][2m+1]}
    v2f w0p[16], w1p[16];
#pragma unroll
    for (int m = 0; m < 16; m++) {
        w0p[m] = (v2f){W_hh[jj * HID + 2*m], W_hh[jj * HID + 2*m + 1]};
        w1p[m] = (v2f){W_hh[(jj+16) * HID + 2*m], W_hh[(jj+16) * HID + 2*m + 1]};
    }
    const float sb0 = b_ih[jj]      + b_hh[jj];
    const float sb1 = b_ih[jj + 16] + b_hh[jj + 16];

    const float* bps = bagf + (size_t)b * 64;

    // length: 4 strided reads + 4 ballots; 16-bit nibble per sample slot
    unsigned long long mm0 = __ballot(bps[jj]      < 4095.5f);
    unsigned long long mm1 = __ballot(bps[jj + 16] < 4095.5f);
    unsigned long long mm2 = __ballot(bps[jj + 32] < 4095.5f);
    unsigned long long mm3 = __ballot(bps[jj + 48] < 4095.5f);
    const int sh = sl * 16;
    const int len = __popc((unsigned)((mm0 >> sh) & 0xFFFFu))
                  + __popc((unsigned)((mm1 >> sh) & 0xFFFFu))
                  + __popc((unsigned)((mm2 >> sh) & 0xFFFFu))
                  + __popc((unsigned)((mm3 >> sh) & 0xFFFFu));

    hbuf[ib][jj]      = 0.f;
    hbuf[ib][jj + 16] = 0.f;
    asm volatile("s_waitcnt lgkmcnt(0)" ::: "memory");   // wave-local fence

    // software pipeline: idx depth-2, pv depth-1
    int   idxB = (int)bps[0];
    int   idxC = (int)bps[1];
    float pv0 = proj[idxB * HID + jj];
    float pv1 = proj[idxB * HID + jj + 16];

    float h0 = 0.f, h1 = 0.f;
    for (int t = 0; t < MAXLEN; t++) {
        // issue next-step loads first; they stay in flight across the fence
        const int t2 = (t + 2 < MAXLEN) ? (t + 2) : (MAXLEN - 1);
        const int idxD = (int)bps[t2];
        const float pv0n = proj[idxC * HID + jj];
        const float pv1n = proj[idxC * HID + jj + 16];

        const float4* hb4 = (const float4*)hbuf[ib];
        v2f a0 = (v2f){0.f, 0.f}, a1 = a0, c0 = a0, c1 = a0;
#pragma unroll
        for (int m = 0; m < 8; m += 2) {
            float4 u = hb4[m], v = hb4[m + 1];
            v2f ulo = (v2f){u.x, u.y}, uhi = (v2f){u.z, u.w};
            v2f vlo = (v2f){v.x, v.y}, vhi = (v2f){v.z, v.w};
            a0 = __builtin_elementwise_fma(w0p[2*m],     ulo, a0);
            a0 = __builtin_elementwise_fma(w0p[2*m + 1], uhi, a0);
            a1 = __builtin_elementwise_fma(w1p[2*m],     ulo, a1);
            a1 = __builtin_elementwise_fma(w1p[2*m + 1], uhi, a1);
            c0 = __builtin_elementwise_fma(w0p[2*m + 2], vlo, c0);
            c0 = __builtin_elementwise_fma(w0p[2*m + 3], vhi, c0);
            c1 = __builtin_elementwise_fma(w1p[2*m + 2], vlo, c1);
            c1 = __builtin_elementwise_fma(w1p[2*m + 3], vhi, c1);
        }
        v2f t0 = a0 + c0;
        v2f t1 = a1 + c1;
        float s0 = sb0 + pv0 + t0.x + t0.y;
        float s1 = sb1 + pv1 + t1.x + t1.y;

        // tanh(s) = 1 - 2/(e^{2s}+1); robust at both extremes, no clamp
        float e0 = __expf(2.f * s0);
        float e1 = __expf(2.f * s1);
        float th0 = 1.f - 2.f * __builtin_amdgcn_rcpf(e0 + 1.f);
        float th1 = 1.f - 2.f * __builtin_amdgcn_rcpf(e1 + 1.f);

        h0 = (t < len) ? th0 : h0;
        h1 = (t < len) ? th1 : h1;

        hbuf[ib][jj]      = h0;
        hbuf[ib][jj + 16] = h1;
        asm volatile("s_waitcnt lgkmcnt(0)" ::: "memory");

        pv0 = pv0n; pv1 = pv1n; idxC = idxD;
    }

    out_h[(size_t)b * HID + jj]      = h0;
    out_h[(size_t)b * HID + jj + 16] = h1;
}

// ---------------- Fallback RNN (R4 exact) if ws can't hold proj ----------------
__global__ __launch_bounds__(128, 4) void rnn_kernel_noproj(
    const float* __restrict__ emb, const float* __restrict__ bagf,
    const float* __restrict__ W_ih, const float* __restrict__ W_hh,
    const float* __restrict__ b_ih, const float* __restrict__ b_hh,
    float* __restrict__ out_h)
{
    __shared__ float hbuf[4][32];
    const int tid = threadIdx.x;
    const int ib  = tid >> 5;
    const int j   = tid & 31;
    const int b   = blockIdx.x * 4 + ib;

    float wih[EMB];
#pragma unroll
    for (int k = 0; k < EMB; k++) wih[k] = W_ih[j * EMB + k];
    float whh[HID];
#pragma unroll
    for (int k = 0; k < HID; k++) whh[k] = W_hh[j * HID + k];
    const float sbias = b_ih[j] + b_hh[j];

    const float* bp = bagf + (size_t)b * 64;
    unsigned long long m0 = __ballot(bp[j]      < 4095.5f);
    unsigned long long m1 = __ballot(bp[32 + j] < 4095.5f);
    const int half = ib & 1;
    const int len = __popc((unsigned)(m0 >> (half * 32)))
                  + __popc((unsigned)(m1 >> (half * 32)));

    hbuf[ib][j] = 0.f;
    asm volatile("s_waitcnt lgkmcnt(0)" ::: "memory");

    float h = 0.f;
    const float* xb = emb + (size_t)b * (MAXLEN * EMB);
    for (int t = 0; t < MAXLEN; t++) {
        const float4* xp = (const float4*)(xb + t * EMB);
        float4 x0 = xp[0], x1 = xp[1], x2 = xp[2], x3 = xp[3], x4 = xp[4];
        float s = sbias;
        const float4* hb4 = (const float4*)hbuf[ib];
#pragma unroll
        for (int m = 0; m < 8; m++) {
            float4 hv = hb4[m];
            s += whh[4*m+0]*hv.x + whh[4*m+1]*hv.y
               + whh[4*m+2]*hv.z + whh[4*m+3]*hv.w;
        }
        s += wih[0]*x0.x + wih[1]*x0.y + wih[2]*x0.z + wih[3]*x0.w;
        s += wih[4]*x1.x + wih[5]*x1.y + wih[6]*x1.z + wih[7]*x1.w;
        s += wih[8]*x2.x + wih[9]*x2.y + wih[10]*x2.z + wih[11]*x2.w;
        s += wih[12]*x3.x + wih[13]*x3.y + wih[14]*x3.z + wih[15]*x3.w;
        s += wih[16]*x4.x + wih[17]*x4.y + wih[18]*x4.z + wih[19]*x4.w;
        s = fminf(fmaxf(s, -9.f), 9.f);
        float e = __expf(2.f * s);
        float th = (e - 1.f) * __builtin_amdgcn_rcpf(e + 1.f);
        h = (t < len) ? th : h;
        hbuf[ib][j] = h;
        asm volatile("s_waitcnt lgkmcnt(0)" ::: "memory");
    }
    out_h[(size_t)b * HID + j] = h;
}

extern "C" void kernel_launch(void* const* d_in, const int* in_sizes, int n_in,
                              void* d_out, int out_size, void* d_ws, size_t ws_size,
                              hipStream_t stream) {
    const int*   chars     = (const int*)d_in[0];
    const int*   colors    = (const int*)d_in[1];
    const float* emb_table = (const float*)d_in[2];
    const float* W_ih      = (const float*)d_in[3];
    const float* W_hh      = (const float*)d_in[4];
    const float* b_ih      = (const float*)d_in[5];
    const float* b_hh      = (const float*)d_in[6];

    const int B = in_sizes[0] / HW;      // 8192

    float* out     = (float*)d_out;
    float* out_h   = out;                                    // [B, 32]
    float* out_emb = out + (size_t)B * HID;                  // [B, 64, 20]
    float* out_bag = out_emb + (size_t)B * MAXLEN * EMB;     // [B, 64]

    const size_t proj_bytes = (size_t)(PADID + 1) * HID * sizeof(float);

    bag_emb_kernel<<<B / 4, 256, 0, stream>>>(chars, colors, emb_table, out_emb, out_bag);

    if (ws_size >= proj_bytes) {         // ws_size is fixed -> same path every call
        float* proj = (float*)d_ws;
        proj_kernel<<<(PADID + 1 + 3) / 4, 128, 0, stream>>>(emb_table, W_ih, proj);
        rnn_kernel<<<B / 8, 128, 0, stream>>>(proj, out_bag, W_hh, b_ih, b_hh, out_h);
    } else {
        rnn_kernel_noproj<<<B / 4, 128, 0, stream>>>(out_emb, out_bag, W_ih, W_hh,
                                                     b_ih, b_hh, out_h);
    }
}

// Round 12
// 185.590 us; speedup vs baseline: 1.1889x; 1.0407x over previous
//
#include <hip/hip_runtime.h>

#define HW 1659      // 21*79
#define PADID 4096
#define EMB 20
#define HID 32
#define MAXLEN 64

typedef float v2f __attribute__((ext_vector_type(2)));

// ---------------- Kernel 0: proj[g][j] = emb_table[g] . W_ih[j]  ---------------
__global__ __launch_bounds__(128) void proj_kernel(
    const float* __restrict__ emb_table, const float* __restrict__ W_ih,
    float* __restrict__ proj)
{
    const int tid = threadIdx.x;
    const int g = blockIdx.x * 4 + (tid >> 5);
    const int j = tid & 31;
    if (g > PADID) return;               // 4097 rows (row 4096 = zeros)
    const float* er = emb_table + (size_t)g * EMB;
    const float* wr = W_ih + j * EMB;
    float s = 0.f;
#pragma unroll
    for (int k = 0; k < EMB; k++) s += wr[k] * er[k];
    proj[(size_t)g * HID + j] = s;
}

// ---------------- Kernel 1: block-per-sample, HOISTED loads ----------------
// All global loads (4 int4/lane + peel/tail) issued BEFORE the LDS zero +
// barrier: max memory-level parallelism, latency hidden behind LDS init.
// Then pure LDS byte-scatter (idempotent). Proven correct in R8/R9.
__global__ __launch_bounds__(256) void bag_emb_kernel(
    const int* __restrict__ chars, const int* __restrict__ colors,
    const float* __restrict__ emb_table,
    float* __restrict__ out_emb, float* __restrict__ out_bag)
{
    __shared__ unsigned char pres[4096];
    __shared__ int bagl[64];
    __shared__ int wsum[4];

    const int b   = blockIdx.x;
    const int tid = threadIdx.x;
    const int lane = tid & 63;
    const int wv   = tid >> 6;

    // ---- hoisted global loads (issue before LDS init/barrier) ----
    const int base = b * HW;
    const int pe = (4 - (base & 3)) & 3;          // peel to 16B alignment
    const int nv = (HW - pe) >> 2;                // 413/414 int4 groups
    const int nt = HW - pe - (nv << 2);           // tail 0..3
    const int4* c4 = (const int4*)(chars + base + pe);
    const int4* k4 = (const int4*)(colors + base + pe);

    int4 ca = c4[tid], ka = k4[tid];              // tid < nv always (nv>=413)
    const bool has2 = (tid + 256) < nv;
    const int i2 = has2 ? tid + 256 : tid;
    int4 cb = c4[i2], kb = k4[i2];
    int gp = -1, gt = -1;
    if (tid < pe) gp = (chars[base + tid] << 4) + colors[base + tid];
    if (tid < nt) {
        int i = base + pe + (nv << 2) + tid;
        gt = (chars[i] << 4) + colors[i];
    }

    ((uint4*)pres)[tid] = make_uint4(0u, 0u, 0u, 0u);
    if (tid < 64) bagl[tid] = PADID;
    __syncthreads();

    // ---- scatter presence bytes (idempotent, no atomics) ----
    pres[(ca.x << 4) + ka.x] = 1;
    pres[(ca.y << 4) + ka.y] = 1;
    pres[(ca.z << 4) + ka.z] = 1;
    pres[(ca.w << 4) + ka.w] = 1;
    if (has2) {
        pres[(cb.x << 4) + kb.x] = 1;
        pres[(cb.y << 4) + kb.y] = 1;
        pres[(cb.z << 4) + kb.z] = 1;
        pres[(cb.w << 4) + kb.w] = 1;
    }
    if (gp >= 0) pres[gp] = 1;
    if (gt >= 0) pres[gt] = 1;
    __syncthreads();

    // ---- each thread owns 16 ids; count + block exclusive scan ----
    uint4 w4 = ((const uint4*)pres)[tid];
    const unsigned M = 0x01010101u;
    int cnt = __popc(w4.x & M) + __popc(w4.y & M)
            + __popc(w4.z & M) + __popc(w4.w & M);

    int pre = cnt;
#pragma unroll
    for (int d = 1; d < 64; d <<= 1) {
        int v = __shfl_up(pre, d, 64);
        if (lane >= d) pre += v;
    }
    if (lane == 63) wsum[wv] = pre;
    __syncthreads();
    int wbase = 0;
#pragma unroll
    for (int w2 = 0; w2 < 4; w2++) wbase += (w2 < wv) ? wsum[w2] : 0;
    int p = wbase + pre - cnt;

    unsigned wrd[4] = {w4.x, w4.y, w4.z, w4.w};
#pragma unroll
    for (int c = 0; c < 4; c++) {
#pragma unroll
        for (int k = 0; k < 4; k++) {
            if ((wrd[c] >> (8 * k)) & 1) {
                if (p < 64) bagl[p] = 16 * tid + 4 * c + k;
                p++;
            }
        }
    }
    __syncthreads();

    if (tid < 64) out_bag[(size_t)b * 64 + tid] = (float)bagl[tid];

    const float4* tab4 = (const float4*)emb_table;
    float4* dst4 = (float4*)(out_emb + (size_t)b * (MAXLEN * EMB));
    for (int q = tid; q < MAXLEN * 5; q += 256) {
        int t = q / 5;
        int m = q - t * 5;
        int row = bagl[t];
        dst4[q] = tab4[row * 5 + m];
    }
}

// ---------------- Kernel 2: packed RNN, 2 hidden units/lane, v_pk_fma ----------
// (R11 exact — proven, rnn ~34 us)
__global__ __launch_bounds__(128, 4) void rnn_kernel(
    const float* __restrict__ proj, const float* __restrict__ bagf,
    const float* __restrict__ W_hh,
    const float* __restrict__ b_ih, const float* __restrict__ b_hh,
    float* __restrict__ out_h)
{
    __shared__ float hbuf[8][32];      // 8 samples/block; wave w owns rows 4w..4w+3

    const int tid  = threadIdx.x;
    const int wv   = tid >> 6;
    const int lane = tid & 63;
    const int sl   = lane >> 4;        // sample slot within wave 0..3
    const int ib   = wv * 4 + sl;      // sample slot within block 0..7
    const int jj   = lane & 15;        // handles hidden units jj and jj+16
    const int b    = blockIdx.x * 8 + ib;

    // weights paired over k: w0p[m] = {W_hh[jj][2m], W_hh[jj][2m+1]}
    v2f w0p[16], w1p[16];
#pragma unroll
    for (int m = 0; m < 16; m++) {
        w0p[m] = (v2f){W_hh[jj * HID + 2*m], W_hh[jj * HID + 2*m + 1]};
        w1p[m] = (v2f){W_hh[(jj+16) * HID + 2*m], W_hh[(jj+16) * HID + 2*m + 1]};
    }
    const float sb0 = b_ih[jj]      + b_hh[jj];
    const float sb1 = b_ih[jj + 16] + b_hh[jj + 16];

    const float* bps = bagf + (size_t)b * 64;

    // length: 4 strided reads + 4 ballots; 16-bit nibble per sample slot
    unsigned long long mm0 = __ballot(bps[jj]      < 4095.5f);
    unsigned long long mm1 = __ballot(bps[jj + 16] < 4095.5f);
    unsigned long long mm2 = __ballot(bps[jj + 32] < 4095.5f);
    unsigned long long mm3 = __ballot(bps[jj + 48] < 4095.5f);
    const int sh = sl * 16;
    const int len = __popc((unsigned)((mm0 >> sh) & 0xFFFFu))
                  + __popc((unsigned)((mm1 >> sh) & 0xFFFFu))
                  + __popc((unsigned)((mm2 >> sh) & 0xFFFFu))
                  + __popc((unsigned)((mm3 >> sh) & 0xFFFFu));

    hbuf[ib][jj]      = 0.f;
    hbuf[ib][jj + 16] = 0.f;
    asm volatile("s_waitcnt lgkmcnt(0)" ::: "memory");   // wave-local fence

    // software pipeline: idx depth-2, pv depth-1
    int   idxB = (int)bps[0];
    int   idxC = (int)bps[1];
    float pv0 = proj[idxB * HID + jj];
    float pv1 = proj[idxB * HID + jj + 16];

    float h0 = 0.f, h1 = 0.f;
    for (int t = 0; t < MAXLEN; t++) {
        // issue next-step loads first; they stay in flight across the fence
        const int t2 = (t + 2 < MAXLEN) ? (t + 2) : (MAXLEN - 1);
        const int idxD = (int)bps[t2];
        const float pv0n = proj[idxC * HID + jj];
        const float pv1n = proj[idxC * HID + jj + 16];

        const float4* hb4 = (const float4*)hbuf[ib];
        v2f a0 = (v2f){0.f, 0.f}, a1 = a0, c0 = a0, c1 = a0;
#pragma unroll
        for (int m = 0; m < 8; m += 2) {
            float4 u = hb4[m], v = hb4[m + 1];
            v2f ulo = (v2f){u.x, u.y}, uhi = (v2f){u.z, u.w};
            v2f vlo = (v2f){v.x, v.y}, vhi = (v2f){v.z, v.w};
            a0 = __builtin_elementwise_fma(w0p[2*m],     ulo, a0);
            a0 = __builtin_elementwise_fma(w0p[2*m + 1], uhi, a0);
            a1 = __builtin_elementwise_fma(w1p[2*m],     ulo, a1);
            a1 = __builtin_elementwise_fma(w1p[2*m + 1], uhi, a1);
            c0 = __builtin_elementwise_fma(w0p[2*m + 2], vlo, c0);
            c0 = __builtin_elementwise_fma(w0p[2*m + 3], vhi, c0);
            c1 = __builtin_elementwise_fma(w1p[2*m + 2], vlo, c1);
            c1 = __builtin_elementwise_fma(w1p[2*m + 3], vhi, c1);
        }
        v2f t0 = a0 + c0;
        v2f t1 = a1 + c1;
        float s0 = sb0 + pv0 + t0.x + t0.y;
        float s1 = sb1 + pv1 + t1.x + t1.y;

        // tanh(s) = 1 - 2/(e^{2s}+1); robust at both extremes, no clamp
        float e0 = __expf(2.f * s0);
        float e1 = __expf(2.f * s1);
        float th0 = 1.f - 2.f * __builtin_amdgcn_rcpf(e0 + 1.f);
        float th1 = 1.f - 2.f * __builtin_amdgcn_rcpf(e1 + 1.f);

        h0 = (t < len) ? th0 : h0;
        h1 = (t < len) ? th1 : h1;

        hbuf[ib][jj]      = h0;
        hbuf[ib][jj + 16] = h1;
        asm volatile("s_waitcnt lgkmcnt(0)" ::: "memory");

        pv0 = pv0n; pv1 = pv1n; idxC = idxD;
    }

    out_h[(size_t)b * HID + jj]      = h0;
    out_h[(size_t)b * HID + jj + 16] = h1;
}

// ---------------- Fallback RNN (R4 exact) if ws can't hold proj ----------------
__global__ __launch_bounds__(128, 4) void rnn_kernel_noproj(
    const float* __restrict__ emb, const float* __restrict__ bagf,
    const float* __restrict__ W_ih, const float* __restrict__ W_hh,
    const float* __restrict__ b_ih, const float* __restrict__ b_hh,
    float* __restrict__ out_h)
{
    __shared__ float hbuf[4][32];
    const int tid = threadIdx.x;
    const int ib  = tid >> 5;
    const int j   = tid & 31;
    const int b   = blockIdx.x * 4 + ib;

    float wih[EMB];
#pragma unroll
    for (int k = 0; k < EMB; k++) wih[k] = W_ih[j * EMB + k];
    float whh[HID];
#pragma unroll
    for (int k = 0; k < HID; k++) whh[k] = W_hh[j * HID + k];
    const float sbias = b_ih[j] + b_hh[j];

    const float* bp = bagf + (size_t)b * 64;
    unsigned long long m0 = __ballot(bp[j]      < 4095.5f);
    unsigned long long m1 = __ballot(bp[32 + j] < 4095.5f);
    const int half = ib & 1;
    const int len = __popc((unsigned)(m0 >> (half * 32)))
                  + __popc((unsigned)(m1 >> (half * 32)));

    hbuf[ib][j] = 0.f;
    asm volatile("s_waitcnt lgkmcnt(0)" ::: "memory");

    float h = 0.f;
    const float* xb = emb + (size_t)b * (MAXLEN * EMB);
    for (int t = 0; t < MAXLEN; t++) {
        const float4* xp = (const float4*)(xb + t * EMB);
        float4 x0 = xp[0], x1 = xp[1], x2 = xp[2], x3 = xp[3], x4 = xp[4];
        float s = sbias;
        const float4* hb4 = (const float4*)hbuf[ib];
#pragma unroll
        for (int m = 0; m < 8; m++) {
            float4 hv = hb4[m];
            s += whh[4*m+0]*hv.x + whh[4*m+1]*hv.y
               + whh[4*m+2]*hv.z + whh[4*m+3]*hv.w;
        }
        s += wih[0]*x0.x + wih[1]*x0.y + wih[2]*x0.z + wih[3]*x0.w;
        s += wih[4]*x1.x + wih[5]*x1.y + wih[6]*x1.z + wih[7]*x1.w;
        s += wih[8]*x2.x + wih[9]*x2.y + wih[10]*x2.z + wih[11]*x2.w;
        s += wih[12]*x3.x + wih[13]*x3.y + wih[14]*x3.z + wih[15]*x3.w;
        s += wih[16]*x4.x + wih[17]*x4.y + wih[18]*x4.z + wih[19]*x4.w;
        s = fminf(fmaxf(s, -9.f), 9.f);
        float e = __expf(2.f * s);
        float th = (e - 1.f) * __builtin_amdgcn_rcpf(e + 1.f);
        h = (t < len) ? th : h;
        hbuf[ib][j] = h;
        asm volatile("s_waitcnt lgkmcnt(0)" ::: "memory");
    }
    out_h[(size_t)b * HID + j] = h;
}

extern "C" void kernel_launch(void* const* d_in, const int* in_sizes, int n_in,
                              void* d_out, int out_size, void* d_ws, size_t ws_size,
                              hipStream_t stream) {
    const int*   chars     = (const int*)d_in[0];
    const int*   colors    = (const int*)d_in[1];
    const float* emb_table = (const float*)d_in[2];
    const float* W_ih      = (const float*)d_in[3];
    const float* W_hh      = (const float*)d_in[4];
    const float* b_ih      = (const float*)d_in[5];
    const float* b_hh      = (const float*)d_in[6];

    const int B = in_sizes[0] / HW;      // 8192

    float* out     = (float*)d_out;
    float* out_h   = out;                                    // [B, 32]
    float* out_emb = out + (size_t)B * HID;                  // [B, 64, 20]
    float* out_bag = out_emb + (size_t)B * MAXLEN * EMB;     // [B, 64]

    const size_t proj_bytes = (size_t)(PADID + 1) * HID * sizeof(float);

    bag_emb_kernel<<<B, 256, 0, stream>>>(chars, colors, emb_table, out_emb, out_bag);

    if (ws_size >= proj_bytes) {         // ws_size is fixed -> same path every call
        float* proj = (float*)d_ws;
        proj_kernel<<<(PADID + 1 + 3) / 4, 128, 0, stream>>>(emb_table, W_ih, proj);
        rnn_kernel<<<B / 8, 128, 0, stream>>>(proj, out_bag, W_hh, b_ih, b_hh, out_h);
    } else {
        rnn_kernel_noproj<<<B / 4, 128, 0, stream>>>(out_emb, out_bag, W_ih, W_hh,
                                                     b_ih, b_hh, out_h);
    }
}

// Round 13
// 183.020 us; speedup vs baseline: 1.2056x; 1.0140x over previous
//
#include <hip/hip_runtime.h>

#define HW 1659      // 21*79
#define PADID 4096
#define EMB 20
#define HID 32
#define MAXLEN 64

typedef float v2f __attribute__((ext_vector_type(2)));

// DPP lane-permute helper (pure VALU, no LDS pipe). CTRL is an immediate.
template <int CTRL>
__device__ __forceinline__ float dppf(float v) {
    return __builtin_bit_cast(float,
        __builtin_amdgcn_update_dpp(0, __builtin_bit_cast(int, v),
                                    CTRL, 0xF, 0xF, true));
}
#define DPP_XOR1 0xB1   // quad_perm [1,0,3,2]
#define DPP_XOR2 0x4E   // quad_perm [2,3,0,1]
#define DPP_XOR7 0x141  // row_half_mirror (xor 7 within 16)
#define DPP_XORF 0x140  // row_mirror      (xor 15 within 16)

// ---------------- Kernel 0: proj[g][j] = emb_table[g] . W_ih[j]  ---------------
__global__ __launch_bounds__(128) void proj_kernel(
    const float* __restrict__ emb_table, const float* __restrict__ W_ih,
    float* __restrict__ proj)
{
    const int tid = threadIdx.x;
    const int g = blockIdx.x * 4 + (tid >> 5);
    const int j = tid & 31;
    if (g > PADID) return;               // 4097 rows (row 4096 = zeros)
    const float* er = emb_table + (size_t)g * EMB;
    const float* wr = W_ih + j * EMB;
    float s = 0.f;
#pragma unroll
    for (int k = 0; k < EMB; k++) s += wr[k] * er[k];
    proj[(size_t)g * HID + j] = s;
}

// ---------------- Kernel 1: block-per-sample, HOISTED loads (R12 exact) --------
__global__ __launch_bounds__(256) void bag_emb_kernel(
    const int* __restrict__ chars, const int* __restrict__ colors,
    const float* __restrict__ emb_table,
    float* __restrict__ out_emb, float* __restrict__ out_bag)
{
    __shared__ unsigned char pres[4096];
    __shared__ int bagl[64];
    __shared__ int wsum[4];

    const int b   = blockIdx.x;
    const int tid = threadIdx.x;
    const int lane = tid & 63;
    const int wv   = tid >> 6;

    const int base = b * HW;
    const int pe = (4 - (base & 3)) & 3;          // peel to 16B alignment
    const int nv = (HW - pe) >> 2;                // 413/414 int4 groups
    const int nt = HW - pe - (nv << 2);           // tail 0..3
    const int4* c4 = (const int4*)(chars + base + pe);
    const int4* k4 = (const int4*)(colors + base + pe);

    int4 ca = c4[tid], ka = k4[tid];              // tid < nv always (nv>=413)
    const bool has2 = (tid + 256) < nv;
    const int i2 = has2 ? tid + 256 : tid;
    int4 cb = c4[i2], kb = k4[i2];
    int gp = -1, gt = -1;
    if (tid < pe) gp = (chars[base + tid] << 4) + colors[base + tid];
    if (tid < nt) {
        int i = base + pe + (nv << 2) + tid;
        gt = (chars[i] << 4) + colors[i];
    }

    ((uint4*)pres)[tid] = make_uint4(0u, 0u, 0u, 0u);
    if (tid < 64) bagl[tid] = PADID;
    __syncthreads();

    pres[(ca.x << 4) + ka.x] = 1;
    pres[(ca.y << 4) + ka.y] = 1;
    pres[(ca.z << 4) + ka.z] = 1;
    pres[(ca.w << 4) + ka.w] = 1;
    if (has2) {
        pres[(cb.x << 4) + kb.x] = 1;
        pres[(cb.y << 4) + kb.y] = 1;
        pres[(cb.z << 4) + kb.z] = 1;
        pres[(cb.w << 4) + kb.w] = 1;
    }
    if (gp >= 0) pres[gp] = 1;
    if (gt >= 0) pres[gt] = 1;
    __syncthreads();

    uint4 w4 = ((const uint4*)pres)[tid];
    const unsigned M = 0x01010101u;
    int cnt = __popc(w4.x & M) + __popc(w4.y & M)
            + __popc(w4.z & M) + __popc(w4.w & M);

    int pre = cnt;
#pragma unroll
    for (int d = 1; d < 64; d <<= 1) {
        int v = __shfl_up(pre, d, 64);
        if (lane >= d) pre += v;
    }
    if (lane == 63) wsum[wv] = pre;
    __syncthreads();
    int wbase = 0;
#pragma unroll
    for (int w2 = 0; w2 < 4; w2++) wbase += (w2 < wv) ? wsum[w2] : 0;
    int p = wbase + pre - cnt;

    unsigned wrd[4] = {w4.x, w4.y, w4.z, w4.w};
#pragma unroll
    for (int c = 0; c < 4; c++) {
#pragma unroll
        for (int k = 0; k < 4; k++) {
            if ((wrd[c] >> (8 * k)) & 1) {
                if (p < 64) bagl[p] = 16 * tid + 4 * c + k;
                p++;
            }
        }
    }
    __syncthreads();

    if (tid < 64) out_bag[(size_t)b * 64 + tid] = (float)bagl[tid];

    const float4* tab4 = (const float4*)emb_table;
    float4* dst4 = (float4*)(out_emb + (size_t)b * (MAXLEN * EMB));
    for (int q = tid; q < MAXLEN * 5; q += 256) {
        int t = q / 5;
        int m = q - t * 5;
        int row = bagl[t];
        dst4[q] = tab4[row * 5 + m];
    }
}

// ---------------- Kernel 2: packed RNN, register-only h, DPP all-gather --------
// 16 lanes/sample, lane jj owns hidden units (2jj, 2jj+1). Per step the 32 h
// values are all-gathered in-register via a 4-round DPP butterfly (30 v_mov_dpp,
// zero LDS, zero fences). Gather order at position m is pair c = jj ^ GMAP[m];
// the weight registers are loaded in that order, making the permutation free.
__global__ __launch_bounds__(128, 2) void rnn_kernel(
    const float* __restrict__ proj, const float* __restrict__ bagf,
    const float* __restrict__ W_hh,
    const float* __restrict__ b_ih, const float* __restrict__ b_hh,
    float* __restrict__ out_h)
{
    const int tid  = threadIdx.x;
    const int wv   = tid >> 6;
    const int lane = tid & 63;
    const int sl   = lane >> 4;        // sample slot within wave 0..3
    const int ib   = wv * 4 + sl;      // sample slot within block 0..7
    const int jj   = lane & 15;        // owns hidden units 2jj, 2jj+1
    const int b    = blockIdx.x * 8 + ib;

    // gather-position -> pair-xor map (butterfly: xor1, xor2, xor7, xor15)
    const int GMAP[16] = {0,1,2,3, 7,6,5,4, 15,14,13,12,11,10,9,8};

    // weights: w0[m]/w1[m] = rows (2jj, 2jj+1), column pair c = jj ^ GMAP[m]
    v2f w0[16], w1[16];
    const float2* wr0 = (const float2*)(W_hh + (2 * jj) * HID);
    const float2* wr1 = (const float2*)(W_hh + (2 * jj + 1) * HID);
#pragma unroll
    for (int m = 0; m < 16; m++) {
        const int c = jj ^ GMAP[m];
        float2 a = wr0[c], bb = wr1[c];
        w0[m] = (v2f){a.x, a.y};
        w1[m] = (v2f){bb.x, bb.y};
    }
    const float sb0 = b_ih[2 * jj]     + b_hh[2 * jj];
    const float sb1 = b_ih[2 * jj + 1] + b_hh[2 * jj + 1];

    const float* bps = bagf + (size_t)b * 64;

    // length: 4 strided reads + 4 ballots; 16-bit nibble per sample slot
    unsigned long long mm0 = __ballot(bps[jj]      < 4095.5f);
    unsigned long long mm1 = __ballot(bps[jj + 16] < 4095.5f);
    unsigned long long mm2 = __ballot(bps[jj + 32] < 4095.5f);
    unsigned long long mm3 = __ballot(bps[jj + 48] < 4095.5f);
    const int sh = sl * 16;
    const int len = __popc((unsigned)((mm0 >> sh) & 0xFFFFu))
                  + __popc((unsigned)((mm1 >> sh) & 0xFFFFu))
                  + __popc((unsigned)((mm2 >> sh) & 0xFFFFu))
                  + __popc((unsigned)((mm3 >> sh) & 0xFFFFu));

    // software pipeline: idx depth-2, pv depth-1 (coalesced float2)
    int idxC = (int)bps[1];
    float2 pv = ((const float2*)(proj + (size_t)((int)bps[0]) * HID))[jj];

    float h0 = 0.f, h1 = 0.f;
    for (int t = 0; t < MAXLEN; t++) {
        const int t2 = (t + 2 < MAXLEN) ? (t + 2) : (MAXLEN - 1);
        const int idxD = (int)bps[t2];
        const float2 pvn = ((const float2*)(proj + (size_t)idxC * HID))[jj];

        // ---- DPP butterfly all-gather: g[m] = pair (jj ^ GMAP[m]) ----
        v2f g[16];
        g[0] = (v2f){h0, h1};
        g[1] = (v2f){dppf<DPP_XOR1>(g[0].x), dppf<DPP_XOR1>(g[0].y)};
        g[2] = (v2f){dppf<DPP_XOR2>(g[0].x), dppf<DPP_XOR2>(g[0].y)};
        g[3] = (v2f){dppf<DPP_XOR2>(g[1].x), dppf<DPP_XOR2>(g[1].y)};
#pragma unroll
        for (int m = 0; m < 4; m++)
            g[4 + m] = (v2f){dppf<DPP_XOR7>(g[m].x), dppf<DPP_XOR7>(g[m].y)};
#pragma unroll
        for (int m = 0; m < 8; m++)
            g[8 + m] = (v2f){dppf<DPP_XORF>(g[m].x), dppf<DPP_XORF>(g[m].y)};

        // ---- 32 pk_fma: rows 2jj and 2jj+1 ----
        v2f a0 = (v2f){0.f, 0.f}, b0 = a0, a1 = a0, b1 = a0;
#pragma unroll
        for (int m = 0; m < 16; m += 2) {
            a0 = __builtin_elementwise_fma(w0[m],     g[m],     a0);
            b0 = __builtin_elementwise_fma(w0[m + 1], g[m + 1], b0);
            a1 = __builtin_elementwise_fma(w1[m],     g[m],     a1);
            b1 = __builtin_elementwise_fma(w1[m + 1], g[m + 1], b1);
        }
        float s0 = sb0 + pv.x + (a0.x + a0.y) + (b0.x + b0.y);
        float s1 = sb1 + pv.y + (a1.x + a1.y) + (b1.x + b1.y);

        // tanh(s) = 1 - 2/(e^{2s}+1); robust at both extremes, no clamp
        float e0 = __expf(2.f * s0);
        float e1 = __expf(2.f * s1);
        float th0 = 1.f - 2.f * __builtin_amdgcn_rcpf(e0 + 1.f);
        float th1 = 1.f - 2.f * __builtin_amdgcn_rcpf(e1 + 1.f);

        h0 = (t < len) ? th0 : h0;
        h1 = (t < len) ? th1 : h1;

        pv = pvn; idxC = idxD;
    }

    ((float2*)(out_h + (size_t)b * HID))[jj] = make_float2(h0, h1);
}

// ---------------- Fallback RNN (R4 exact) if ws can't hold proj ----------------
__global__ __launch_bounds__(128, 4) void rnn_kernel_noproj(
    const float* __restrict__ emb, const float* __restrict__ bagf,
    const float* __restrict__ W_ih, const float* __restrict__ W_hh,
    const float* __restrict__ b_ih, const float* __restrict__ b_hh,
    float* __restrict__ out_h)
{
    __shared__ float hbuf[4][32];
    const int tid = threadIdx.x;
    const int ib  = tid >> 5;
    const int j   = tid & 31;
    const int b   = blockIdx.x * 4 + ib;

    float wih[EMB];
#pragma unroll
    for (int k = 0; k < EMB; k++) wih[k] = W_ih[j * EMB + k];
    float whh[HID];
#pragma unroll
    for (int k = 0; k < HID; k++) whh[k] = W_hh[j * HID + k];
    const float sbias = b_ih[j] + b_hh[j];

    const float* bp = bagf + (size_t)b * 64;
    unsigned long long m0 = __ballot(bp[j]      < 4095.5f);
    unsigned long long m1 = __ballot(bp[32 + j] < 4095.5f);
    const int half = ib & 1;
    const int len = __popc((unsigned)(m0 >> (half * 32)))
                  + __popc((unsigned)(m1 >> (half * 32)));

    hbuf[ib][j] = 0.f;
    asm volatile("s_waitcnt lgkmcnt(0)" ::: "memory");

    float h = 0.f;
    const float* xb = emb + (size_t)b * (MAXLEN * EMB);
    for (int t = 0; t < MAXLEN; t++) {
        const float4* xp = (const float4*)(xb + t * EMB);
        float4 x0 = xp[0], x1 = xp[1], x2 = xp[2], x3 = xp[3], x4 = xp[4];
        float s = sbias;
        const float4* hb4 = (const float4*)hbuf[ib];
#pragma unroll
        for (int m = 0; m < 8; m++) {
            float4 hv = hb4[m];
            s += whh[4*m+0]*hv.x + whh[4*m+1]*hv.y
               + whh[4*m+2]*hv.z + whh[4*m+3]*hv.w;
        }
        s += wih[0]*x0.x + wih[1]*x0.y + wih[2]*x0.z + wih[3]*x0.w;
        s += wih[4]*x1.x + wih[5]*x1.y + wih[6]*x1.z + wih[7]*x1.w;
        s += wih[8]*x2.x + wih[9]*x2.y + wih[10]*x2.z + wih[11]*x2.w;
        s += wih[12]*x3.x + wih[13]*x3.y + wih[14]*x3.z + wih[15]*x3.w;
        s += wih[16]*x4.x + wih[17]*x4.y + wih[18]*x4.z + wih[19]*x4.w;
        s = fminf(fmaxf(s, -9.f), 9.f);
        float e = __expf(2.f * s);
        float th = (e - 1.f) * __builtin_amdgcn_rcpf(e + 1.f);
        h = (t < len) ? th : h;
        hbuf[ib][j] = h;
        asm volatile("s_waitcnt lgkmcnt(0)" ::: "memory");
    }
    out_h[(size_t)b * HID + j] = h;
}

extern "C" void kernel_launch(void* const* d_in, const int* in_sizes, int n_in,
                              void* d_out, int out_size, void* d_ws, size_t ws_size,
                              hipStream_t stream) {
    const int*   chars     = (const int*)d_in[0];
    const int*   colors    = (const int*)d_in[1];
    const float* emb_table = (const float*)d_in[2];
    const float* W_ih      = (const float*)d_in[3];
    const float* W_hh      = (const float*)d_in[4];
    const float* b_ih      = (const float*)d_in[5];
    const float* b_hh      = (const float*)d_in[6];

    const int B = in_sizes[0] / HW;      // 8192

    float* out     = (float*)d_out;
    float* out_h   = out;                                    // [B, 32]
    float* out_emb = out + (size_t)B * HID;                  // [B, 64, 20]
    float* out_bag = out_emb + (size_t)B * MAXLEN * EMB;     // [B, 64]

    const size_t proj_bytes = (size_t)(PADID + 1) * HID * sizeof(float);

    bag_emb_kernel<<<B, 256, 0, stream>>>(chars, colors, emb_table, out_emb, out_bag);

    if (ws_size >= proj_bytes) {         // ws_size is fixed -> same path every call
        float* proj = (float*)d_ws;
        proj_kernel<<<(PADID + 1 + 3) / 4, 128, 0, stream>>>(emb_table, W_ih, proj);
        rnn_kernel<<<B / 8, 128, 0, stream>>>(proj, out_bag, W_hh, b_ih, b_hh, out_h);
    } else {
        rnn_kernel_noproj<<<B / 4, 128, 0, stream>>>(out_emb, out_bag, W_ih, W_hh,
                                                     b_ih, b_hh, out_h);
    }
}